// Round 11
// baseline (2578.397 us; speedup 1.0000x reference)
//
#include <hip/hip_runtime.h>
#include <stdint.h>

typedef unsigned short u16;
typedef unsigned int u32;
typedef unsigned long long u64;
typedef __attribute__((ext_vector_type(4))) float f32x4;
typedef __attribute__((ext_vector_type(8))) short bf16x8;
typedef __attribute__((ext_vector_type(4))) u32 u32x4;

constexpr int kT = 8192;   // sequence length
constexpr int kD = 512;    // word emb dim
constexpr int kH = 2048;   // hidden
constexpr int kH3 = 6144;  // 3*H
constexpr int kS = 512;    // segments
constexpr int kSeg = 16;   // tokens per segment
constexpr int kNWG2 = 256; // persistent WGs for upper GRU
constexpr int kREP = 4;    // h-exchange replicas

__device__ __forceinline__ float bf2f(u16 u) {
  union { float f; u32 u; } v; v.u = ((u32)u) << 16; return v.f;
}
__device__ __forceinline__ u16 f2bf(float f) {
  union { float f; u32 u; } v; v.f = f;
  u32 lsb = (v.u >> 16) & 1u;
  v.u += 0x7fffu + lsb;          // round-to-nearest-even
  return (u16)(v.u >> 16);
}
// cheap packed-bf16 unpack: lo/hi half of a u32 as f32 (2 ops each)
__device__ __forceinline__ float bflo(u32 x) {
  union { float f; u32 u; } v; v.u = x << 16; return v.f;
}
__device__ __forceinline__ float bfhi(u32 x) {
  union { float f; u32 u; } v; v.u = x & 0xffff0000u; return v.f;
}
__device__ __forceinline__ float sigm(float x) { return 1.f / (1.f + expf(-x)); }

// async global->LDS, 16B per lane; LDS dest = wave-uniform base + lane*16
__device__ __forceinline__ void g2l16(const u16* g, u16* l) {
  __builtin_amdgcn_global_load_lds(
      (const __attribute__((address_space(1))) u32*)g,
      (__attribute__((address_space(3))) u32*)l, 16, 0, 0);
}

// device-coherent (sc0 sc1) bypass load/store
__device__ __forceinline__ u32x4 bypass_load16(const u32* p) {
  u32x4 v;
  asm volatile("global_load_dwordx4 %0, %1, off sc0 sc1\n\ts_waitcnt vmcnt(0)"
               : "=&v"(v) : "v"(p) : "memory");
  return v;
}
__device__ __forceinline__ void bypass_store4(u32* p, u32 v) {
  asm volatile("global_store_dword %0, %1, off sc0 sc1" :: "v"(p), "v"(v) : "memory");
}

// ---------------- fused f32 -> bf16 convert (all 7 regions, one launch) ----
struct Cvt7 {
  const float* s[7];
  u16* d[7];
  u32 pref[8];   // prefix sums in float4 units
};
__global__ __launch_bounds__(256) void cvt_all(Cvt7 j, int n4tot) {
  int i = blockIdx.x * 256 + threadIdx.x;
  if (i >= n4tot) return;
  int r = 0;
  while (i >= (int)j.pref[r + 1]) ++r;   // <= 7 iterations
  const int local = i - (int)j.pref[r];
  const float4 v = ((const float4*)j.s[r])[local];
  uint2 o;
  o.x = (u32)f2bf(v.x) | ((u32)f2bf(v.y) << 16);
  o.y = (u32)f2bf(v.z) | ((u32)f2bf(v.w) << 16);
  ((uint2*)j.d[r])[local] = o;
}

// ---------------- bf16 GEMM 128x128  C = A(MxK,lda) * B(NxK,ldb)^T ---------
// 4-deep software-pipelined staging (counted vmcnt + raw s_barrier; never
// drain-0 mid-loop). EPI 1: Obf = bf16(acc)   EPI 2: Obf = bf16(tanh(acc+bias))
template<int EPI>
__global__ __launch_bounds__(256)
void gemm_bt(const u16* __restrict__ A, int lda,
             const u16* __restrict__ B, int ldb,
             u16* __restrict__ Obf, const float* __restrict__ bias,
             int M, int N, int K)
{
  __shared__ u16 ls[4 * 16384];   // 4 bufs x (A 128x64 + B 128x64) = 128 KiB
  const int tid = threadIdx.x;
  const int w = tid >> 6, lane = tid & 63;
  const int wr = w >> 1, wc = w & 1;
  const int arow0 = blockIdx.y * 128;
  const int brow0 = blockIdx.x * 128;
  const int srow = w * 32 + (lane >> 3);
  const int scol = (lane & 7) * 8;
  const u16* gA = A + (size_t)(arow0 + srow) * lda + scol;
  const u16* gB = B + (size_t)(brow0 + srow) * ldb + scol;
  const int sb = w * 32 * 64;     // wave's staging base (rows w*32..)

  f32x4 acc[4][4];
#pragma unroll
  for (int m = 0; m < 4; ++m)
#pragma unroll
    for (int n = 0; n < 4; ++n) acc[m][n] = (f32x4)0.f;

  const int fr = lane & 15;
  const int kq = lane >> 4;
  const int nk = K >> 6;

  auto stage = [&](int buf, int kt) {
    u16* la = &ls[buf * 16384 + sb];
    u16* lb = &ls[buf * 16384 + 8192 + sb];
#pragma unroll
    for (int i = 0; i < 4; ++i) g2l16(gA + (size_t)i * 8 * lda + kt, la + i * 8 * 64);
#pragma unroll
    for (int i = 0; i < 4; ++i) g2l16(gB + (size_t)i * 8 * ldb + kt, lb + i * 8 * 64);
  };

  stage(0, 0);
  if (nk > 1) stage(1, 64);
  if (nk > 2) stage(2, 128);

  for (int i = 0; i < nk; ++i) {
    if (i + 2 < nk) asm volatile("s_waitcnt vmcnt(16)" ::: "memory");
    else            asm volatile("s_waitcnt vmcnt(0)" ::: "memory");
    __builtin_amdgcn_s_barrier();
    __builtin_amdgcn_sched_barrier(0);
    if (i + 3 < nk) stage((i + 3) & 3, (i + 3) * 64);
    const u16* lsA = &ls[(i & 3) * 16384];
    const u16* lsB = lsA + 8192;
#pragma unroll
    for (int kk = 0; kk < 2; ++kk) {
      bf16x8 af[4], bq[4];
#pragma unroll
      for (int m = 0; m < 4; ++m)
        af[m] = *(const bf16x8*)&lsA[(wr * 64 + m * 16 + fr) * 64 + kk * 32 + kq * 8];
#pragma unroll
      for (int n = 0; n < 4; ++n)
        bq[n] = *(const bf16x8*)&lsB[(wc * 64 + n * 16 + fr) * 64 + kk * 32 + kq * 8];
#pragma unroll
      for (int m = 0; m < 4; ++m)
#pragma unroll
        for (int n = 0; n < 4; ++n)
          acc[m][n] = __builtin_amdgcn_mfma_f32_16x16x32_bf16(af[m], bq[n], acc[m][n], 0, 0, 0);
    }
  }

#pragma unroll
  for (int m = 0; m < 4; ++m) {
#pragma unroll
    for (int n = 0; n < 4; ++n) {
      const int row0 = arow0 + wr * 64 + m * 16 + kq * 4;
      const int col = brow0 + wc * 64 + n * 16 + fr;
      if (EPI == 1) {
#pragma unroll
        for (int i = 0; i < 4; ++i)
          Obf[(size_t)(row0 + i) * N + col] = f2bf(acc[m][n][i]);
      } else {
        const float bv = bias[col];
#pragma unroll
        for (int i = 0; i < 4; ++i)
          Obf[(size_t)(row0 + i) * N + col] = f2bf(tanhf(acc[m][n][i] + bv));
      }
    }
  }
}

// ---------------- FUSED gh-GEMM + GRU gates (steps t=1..15) ----------------
// Per block: 64 segs x 64 j-cols, all 3 gates (192 B-rows). Wave w owns
// M-tile w (16 segs) x 12 N-tiles. Same 4-deep pipeline constants as
// gemm_bt (8 g2l16/wave/stage, vmcnt(16)). Epilogue: r/z/n for (seg,j) are
// acc[n]/acc[n+4]/acc[n+8] same lane same reg -> gates in registers.
// h ping-pong: reads h_in, writes h_out (no race).
// XCD swizzle: each XCD owns 4 consecutive N-blocks -> 3MB Wh1 slice
// L2-resident instead of all 25MB thrashing every XCD L2.
__global__ __launch_bounds__(256)
void gh_gates(const u16* __restrict__ h_in, const u16* __restrict__ Wh1b,
              const u16* __restrict__ gi_p, int giStride,
              const float* __restrict__ bi, const float* __restrict__ bh,
              u16* __restrict__ h_out, u16* __restrict__ outs_p, int outsStride)
{
  __shared__ u16 ls[4 * 16384];   // 4 bufs x (A 64x64 + B 192x64) = 128 KiB
  const int tid = threadIdx.x;
  const int w = tid >> 6, lane = tid & 63;
  const int b = blockIdx.x;                   // 256 blocks, flattened
  const int xcd = b & 7, sub = (b >> 3) & 3, by = b >> 5;
  const int bx = xcd * 4 + sub;               // N-block: XCD owns 4 consecutive
  const int j0 = bx * 64, seg0 = by * 64;
  const int srow = lane >> 3, scol = (lane & 7) * 8;
  const u16* gA = h_in + (size_t)(seg0 + w * 16 + srow) * kH + scol;
  const u16* gB[6];
#pragma unroll
  for (int i = 0; i < 6; ++i) {
    const int lb = w * 48 + i * 8 + srow;     // B local row 0..191
    const int grow = (lb >> 6) * kH + j0 + (lb & 63);
    gB[i] = Wh1b + (size_t)grow * kH + scol;
  }
  const int sbA = w * 16 * 64;
  const int sbB = 4096 + w * 48 * 64;

  f32x4 acc[12];
#pragma unroll
  for (int n = 0; n < 12; ++n) acc[n] = (f32x4)0.f;

  const int fr = lane & 15;
  const int kq = lane >> 4;
  constexpr int nk = kH / 64;   // 32

  auto stage = [&](int buf, int kt) {
    u16* base = &ls[buf * 16384];
#pragma unroll
    for (int i = 0; i < 2; ++i) g2l16(gA + (size_t)i * 8 * kH + kt, base + sbA + i * 8 * 64);
#pragma unroll
    for (int i = 0; i < 6; ++i) g2l16(gB[i] + kt, base + sbB + i * 8 * 64);
  };

  stage(0, 0);
  stage(1, 64);
  stage(2, 128);

  for (int i = 0; i < nk; ++i) {
    if (i + 2 < nk) asm volatile("s_waitcnt vmcnt(16)" ::: "memory");
    else            asm volatile("s_waitcnt vmcnt(0)" ::: "memory");
    __builtin_amdgcn_s_barrier();
    __builtin_amdgcn_sched_barrier(0);
    if (i + 3 < nk) stage((i + 3) & 3, (i + 3) * 64);
    const u16* lsA = &ls[(i & 3) * 16384];
    const u16* lsB = lsA + 4096;
#pragma unroll
    for (int kk = 0; kk < 2; ++kk) {
      const bf16x8 af = *(const bf16x8*)&lsA[(w * 16 + fr) * 64 + kk * 32 + kq * 8];
#pragma unroll
      for (int n12 = 0; n12 < 12; ++n12) {
        const bf16x8 bq = *(const bf16x8*)&lsB[(n12 * 16 + fr) * 64 + kk * 32 + kq * 8];
        acc[n12] = __builtin_amdgcn_mfma_f32_16x16x32_bf16(af, bq, acc[n12], 0, 0, 0);
      }
    }
  }

  // ---- fused gates epilogue ----
#pragma unroll
  for (int n = 0; n < 4; ++n) {
    const int jg = j0 + n * 16 + fr;
    const float bir = bi[jg], biz = bi[kH + jg], bin = bi[2 * kH + jg];
    const float bhr = bh[jg], bhz = bh[kH + jg], bhn = bh[2 * kH + jg];
#pragma unroll
    for (int ii = 0; ii < 4; ++ii) {
      const int seg = seg0 + w * 16 + kq * 4 + ii;
      const float ghr = acc[n][ii], ghz = acc[n + 4][ii], ghn = acc[n + 8][ii];
      const size_t gio = (size_t)seg * giStride;
      const float gir = bf2f(gi_p[gio + jg]);
      const float giz = bf2f(gi_p[gio + kH + jg]);
      const float gin = bf2f(gi_p[gio + 2 * kH + jg]);
      const float r = sigm(gir + bir + ghr + bhr);
      const float z = sigm(giz + biz + ghz + bhz);
      const float nn = tanhf(gin + bin + r * (ghn + bhn));
      const float hp = bf2f(h_in[(size_t)seg * kH + jg]);
      const u16 hb = f2bf((1.f - z) * nn + z * hp);
      h_out[(size_t)seg * kH + jg] = hb;
      outs_p[(size_t)seg * outsStride + jg] = hb;
    }
  }
}

// ---------------- lower-GRU gates (t=0 only: h_prev = 0) ----------------
__global__ __launch_bounds__(256) void gru1_gates0(
    const u32* __restrict__ gi32, int segStride,
    const float* __restrict__ bi,
    u16* __restrict__ h_bf, u16* __restrict__ outs_bf)
{
  const int idx = blockIdx.x * 256 + threadIdx.x;  // 512*1024 pairs
  const int seg = idx >> 10, jp = idx & 1023;      // j = 2*jp
  const int gbase = seg * segStride;
  const u32 giz = gi32[gbase + 1024 + jp];
  const u32 gin = gi32[gbase + 2048 + jp];
  const float2 biz = *(const float2*)&bi[kH + 2 * jp];
  const float2 bin = *(const float2*)&bi[2 * kH + 2 * jp];
  float hn[2];
#pragma unroll
  for (int e = 0; e < 2; ++e) {
    const float gz = e ? bfhi(giz) : bflo(giz);
    const float gn = e ? bfhi(gin) : bflo(gin);
    const float z = sigm(gz + (e ? biz.y : biz.x));
    const float n = tanhf(gn + (e ? bin.y : bin.x));
    hn[e] = (1.f - z) * n;
  }
  const u32 packed = (u32)f2bf(hn[0]) | ((u32)f2bf(hn[1]) << 16);
  ((u32*)h_bf)[seg * 1024 + jp] = packed;
  ((u32*)outs_bf)[(size_t)(seg * kSeg) * 1024 + jp] = packed;
}

// ---------------- degenerate softmax weight + per-segment column max ----------------
__global__ __launch_bounds__(256) void seg_weight_max(
    const u16* __restrict__ embh, const float* __restrict__ wa,
    u16* __restrict__ seg_bf)
{
  __shared__ float wrow[16];
  const int s = blockIdx.x, tid = threadIdx.x;
  const int w = tid >> 6, lane = tid & 63;
#pragma unroll
  for (int rr = 0; rr < 4; ++rr) {
    const int r = w * 4 + rr;
    const u16* row = embh + ((size_t)s * kSeg + r) * kH;
    float p = 0.f;
#pragma unroll
    for (int k = 0; k < 32; ++k) {
      const int c = lane + 64 * k;
      p += bf2f(row[c]) * wa[c];
    }
#pragma unroll
    for (int off = 32; off; off >>= 1) p += __shfl_down(p, off, 64);
    if (lane == 0) { const float e = expf(p); wrow[r] = e / (e + 1e-4f); }
  }
  __syncthreads();
#pragma unroll
  for (int i = 0; i < 8; ++i) {
    const int c = tid + 256 * i;
    float m = -1e30f;
#pragma unroll
    for (int r = 0; r < 16; ++r)
      m = fmaxf(m, wrow[r] * bf2f(embh[((size_t)s * kSeg + r) * kH + c]));
    seg_bf[(size_t)s * kH + c] = f2bf(m);
  }
}

// ---------------- upper GRU: persistent, 512 steps (r9 v5, unchanged) ------
__global__ __launch_bounds__(512)
void gru2_persistent(const u16* __restrict__ Wh2bf, const u16* __restrict__ gi2b,
                     const float* __restrict__ bi2, const float* __restrict__ bh2,
                     u32* __restrict__ hx,        // [2][kREP][2048] tagged u32
                     u16* __restrict__ outs2)     // 512*2048 bf16
{
  __shared__ u32 hlb[2][1024];                // 8 KiB: h packed pairs, dbuf
  __shared__ float gil_all[512 * 24];         // 48 KiB gi2 slice
  __shared__ u32 hnlt[8];                     // tagged per-wave results
  const int wg = blockIdx.x, tid = threadIdx.x;
  const int g0 = wg * 8;
  const int rep = wg & (kREP - 1);
  const int w = tid >> 6, lane = tid & 63;
  const int jj = g0 + w;                      // this wave's output element

  // ---- weights: r/z/n rows of element jj; cols q*512 + lane*8 .. +8 ----
  u32 wr_[16], wz_[16], wn_[16];
  {
    const u32* rr = (const u32*)(Wh2bf + (size_t)jj * kH);
    const u32* rz = (const u32*)(Wh2bf + (size_t)(kH + jj) * kH);
    const u32* rn = (const u32*)(Wh2bf + (size_t)(2 * kH + jj) * kH);
#pragma unroll
    for (int q = 0; q < 4; ++q)
#pragma unroll
      for (int i = 0; i < 4; ++i) {
        const int idx = q * 256 + lane * 4 + i;
        wr_[q * 4 + i] = rr[idx];
        wz_[q * 4 + i] = rz[idx];
        wn_[q * 4 + i] = rn[idx];
      }
  }
  for (int i = tid; i < 512 * 24; i += 512) {
    const int t = i / 24, idx = i - t * 24;
    gil_all[i] = bf2f(gi2b[(size_t)t * kH3 + (idx >> 3) * kH + g0 + (idx & 7)]);
  }
  const float bir = bi2[jj], biz = bi2[kH + jj], bin = bi2[2 * kH + jj];
  const float bhr = bh2[jj], bhz = bh2[kH + jj], bhn = bh2[2 * kH + jj];
  if (tid < 8) hnlt[tid] = 0;
  __syncthreads();

  for (int t = 0; t < 512; ++t) {
    const int par = t & 1;
    const u32 want = (u32)t & 0xffffu;
    const u32* p = hx + ((size_t)par * kREP + rep) * 2048 + 4 * tid;
    u32x4 v = bypass_load16(p);
    for (;;) {
      const u32 bad = ((v.x ^ want) | (v.y ^ want) | (v.z ^ want) | (v.w ^ want)) & 0xffffu;
      if (!__any((int)bad)) break;
      if (bad) v = bypass_load16(p);
    }
    hlb[par][2 * tid]     = (v.x >> 16) | (v.y & 0xffff0000u);
    hlb[par][2 * tid + 1] = (v.z >> 16) | (v.w & 0xffff0000u);
    __syncthreads();
    const uint4* hp4 = (const uint4*)&hlb[par][0];
    float ar = 0.f, az = 0.f, an = 0.f;
#pragma unroll
    for (int q = 0; q < 4; ++q) {
      const uint4 hv = hp4[q * 64 + lane];
      const float hf[8] = { bflo(hv.x), bfhi(hv.x), bflo(hv.y), bfhi(hv.y),
                            bflo(hv.z), bfhi(hv.z), bflo(hv.w), bfhi(hv.w) };
#pragma unroll
      for (int i = 0; i < 4; ++i) {
        const u32 wrv = wr_[q * 4 + i], wzv = wz_[q * 4 + i], wnv = wn_[q * 4 + i];
        ar += bflo(wrv) * hf[2 * i] + bfhi(wrv) * hf[2 * i + 1];
        az += bflo(wzv) * hf[2 * i] + bfhi(wzv) * hf[2 * i + 1];
        an += bflo(wnv) * hf[2 * i] + bfhi(wnv) * hf[2 * i + 1];
      }
    }
#pragma unroll
    for (int off = 32; off; off >>= 1) {
      ar += __shfl_down(ar, off, 64);
      az += __shfl_down(az, off, 64);
      an += __shfl_down(an, off, 64);
    }
    if (lane == 0) {
      const float r = sigm(gil_all[t * 24 + w] + bir + ar + bhr);
      const float z = sigm(gil_all[t * 24 + 8 + w] + biz + az + bhz);
      const float n = tanhf(gil_all[t * 24 + 16 + w] + bin + r * (an + bhn));
      const u32 hw = hlb[par][jj >> 1];
      const float hprev = (jj & 1) ? bfhi(hw) : bflo(hw);
      const u16 hb = f2bf((1.f - z) * n + z * hprev);
      const u32 word = ((u32)hb << 16) | ((u32)(t + 1) & 0xffffu);
      __hip_atomic_store(&hnlt[w], word, __ATOMIC_RELAXED, __HIP_MEMORY_SCOPE_WORKGROUP);
    }
    if (w == 0) {
      const u32 want1 = (u32)(t + 1) & 0xffffu;
      u32 x = 0;
      if (lane < 8) {
        for (;;) {
          x = __hip_atomic_load(&hnlt[lane], __ATOMIC_RELAXED, __HIP_MEMORY_SCOPE_WORKGROUP);
          if ((x & 0xffffu) == want1) break;
        }
      }
      const u32 word = __shfl(x, lane & 7, 64);
      if (lane < 4 * 8) {
        const int orep = lane >> 3;
        bypass_store4(hx + ((size_t)(1 - par) * kREP + orep) * 2048 + g0 + (lane & 7), word);
      }
      if (lane < 8) outs2[(size_t)t * kH + g0 + lane] = (u16)(x >> 16);
    }
  }
}

// ---------------- w2 then final column max ----------------
__global__ void calc_w2(const u16* __restrict__ e2, const float* __restrict__ wa2,
                        float* __restrict__ w2) {
  const int s = blockIdx.x, lane = threadIdx.x;  // 64 threads
  float p = 0.f;
#pragma unroll
  for (int k = 0; k < 32; ++k) {
    const int c = lane + 64 * k;
    p += bf2f(e2[(size_t)s * kH + c]) * wa2[c];
  }
#pragma unroll
  for (int off = 32; off; off >>= 1) p += __shfl_down(p, off, 64);
  if (lane == 0) { const float e = expf(p); w2[s] = e / (e + 1e-4f); }
}

__global__ void final_max(const u16* __restrict__ e2, const float* __restrict__ w2,
                          float* __restrict__ out) {
  const int j = blockIdx.x * blockDim.x + threadIdx.x;  // 2048
  float m = -1e30f;
  for (int s = 0; s < 512; ++s)
    m = fmaxf(m, w2[s] * bf2f(e2[(size_t)s * kH + j]));
  out[j] = m;
}

// ---------------- host ----------------
extern "C" void kernel_launch(void* const* d_in, const int* in_sizes, int n_in,
                              void* d_out, int out_size, void* d_ws, size_t ws_size,
                              hipStream_t stream)
{
  (void)in_sizes; (void)n_in; (void)out_size;
  const float* sent = (const float*)d_in[0];
  const float* Wi1f = (const float*)d_in[1];
  const float* Wh1f = (const float*)d_in[2];
  const float* bi1  = (const float*)d_in[3];
  const float* bh1  = (const float*)d_in[4];
  const float* Wi2f = (const float*)d_in[5];
  const float* Wh2f = (const float*)d_in[6];
  const float* bi2  = (const float*)d_in[7];
  const float* bh2  = (const float*)d_in[8];
  const float* Wlf  = (const float*)d_in[9];
  const float* bl   = (const float*)d_in[10];
  const float* wa   = (const float*)d_in[11];
  const float* Wl2f = (const float*)d_in[12];
  const float* bl2  = (const float*)d_in[13];
  const float* wa2  = (const float*)d_in[14];
  float* out = (float*)d_out;

  char* base = (char*)d_ws;
  size_t off = 0;
  auto alloc = [&](size_t b) { char* p = base + off; off += (b + 255) & ~(size_t)255; return p; };
  u16* sent_bf = (u16*)alloc((size_t)kT * kD * 2);   // dead after GI/phase B -> embh alias
  u16* Wi1b    = (u16*)alloc((size_t)kH3 * kD * 2);
  u16* Wh1b    = (u16*)alloc((size_t)kH3 * kH * 2);
  u16* Wi2b    = (u16*)alloc((size_t)kH3 * kH * 2);
  u16* Wh2b    = (u16*)alloc((size_t)kH3 * kH * 2);
  u16* Wlb     = (u16*)alloc((size_t)kH * kH * 2);
  u16* Wl2b    = (u16*)alloc((size_t)kH * kH * 2);
  u16* gi_buf  = (u16*)alloc((size_t)kS * kH3 * 2);  // per-step fallback
  u16* h1a     = (u16*)alloc((size_t)kS * kH * 2);   // h ping-pong
  u16* h1c     = (u16*)alloc((size_t)kS * kH * 2);
  u16* outs_bf = (u16*)alloc((size_t)kT * kH * 2);
  u16* seg_bf  = (u16*)alloc((size_t)kS * kH * 2);
  u32* hx      = (u32*)alloc((size_t)2 * kREP * 2048 * 4);
  u16* outs2   = (u16*)alloc((size_t)kS * kH * 2);
  u16* e2b     = (u16*)alloc((size_t)kS * kH * 2);
  float* w2    = (float*)alloc(kS * 4);
  // optional fused-gi buffer (100.7 MB): engage only if ws is big enough
  const size_t off_before_gi = off;
  u16* gi_all  = (u16*)alloc((size_t)kT * kH3 * 2);
  const bool fused_gi = (off <= ws_size);
  if (!fused_gi) off = off_before_gi;
  // aliases over dead regions
  u16* embh = sent_bf;   // 33.5 MB fits in sent_bf+Wi1b+Wh1b (39.8 MB)
  u16* gi2b = gi_buf;

  (void)hipMemsetAsync(hx, 0, (size_t)2 * kREP * 2048 * 4, stream);

  // ---- fused conversion: all 7 regions, one launch ----
  {
    Cvt7 j;
    const float* srcs[7] = { sent, Wi1f, Wh1f, Wi2f, Wh2f, Wlf, Wl2f };
    u16* dsts[7] = { sent_bf, Wi1b, Wh1b, Wi2b, Wh2b, Wlb, Wl2b };
    const u32 n4s[7] = { kT * kD / 4, kH3 * kD / 4, kH3 * kH / 4, kH3 * kH / 4,
                         kH3 * kH / 4, kH * kH / 4, kH * kH / 4 };
    u32 acc = 0;
    for (int r = 0; r < 7; ++r) { j.s[r] = srcs[r]; j.d[r] = dsts[r]; j.pref[r] = acc; acc += n4s[r]; }
    j.pref[7] = acc;
    cvt_all<<<dim3((acc + 255) / 256), dim3(256), 0, stream>>>(j, (int)acc);
  }

  // ---- phase B: lower GRU, 16 batched steps over 512 independent chains ----
  if (fused_gi) {
    gemm_bt<1><<<dim3(kH3 / 128, kT / 128), dim3(256), 0, stream>>>(
        sent_bf, kD, Wi1b, kD, gi_all, nullptr, kT, kH3, kD);
  }
  u16* h_cur = h1a;
  u16* h_nxt = h1c;
  for (int t = 0; t < kSeg; ++t) {
    const u16* gi_p;
    int giStride;
    if (fused_gi) {
      gi_p = gi_all + (size_t)t * kH3;       // token = seg*16 + t
      giStride = kSeg * kH3;
    } else {
      gemm_bt<1><<<dim3(kH3 / 128, kS / 128), dim3(256), 0, stream>>>(
          sent_bf + t * kD, kSeg * kD, Wi1b, kD, gi_buf, nullptr, kS, kH3, kD);
      gi_p = gi_buf;
      giStride = kH3;
    }
    if (t == 0) {
      gru1_gates0<<<dim3(kS * kH / 512), dim3(256), 0, stream>>>(
          (const u32*)gi_p, giStride / 2, bi1, h_cur, outs_bf);
    } else {
      gh_gates<<<dim3(256), dim3(256), 0, stream>>>(
          h_cur, Wh1b, gi_p, giStride, bi1, bh1,
          h_nxt, outs_bf + (size_t)t * kH, kSeg * kH);
      u16* tmp = h_cur; h_cur = h_nxt; h_nxt = tmp;
    }
  }
  // ---- phase C: emb_h = tanh(outs @ Wl^T + bl) ----
  gemm_bt<2><<<dim3(kH / 128, kT / 128), dim3(256), 0, stream>>>(
      outs_bf, kH, Wlb, kH, embh, bl, kT, kH, kH);
  // ---- phase D: w, weighted, segment max ----
  seg_weight_max<<<dim3(kS), dim3(256), 0, stream>>>(embh, wa, seg_bf);
  // ---- phase E: gi2 = seg @ Wi2^T (bf16) ----
  gemm_bt<1><<<dim3(kH3 / 128, kS / 128), dim3(256), 0, stream>>>(
      seg_bf, kH, Wi2b, kH, gi2b, nullptr, kS, kH3, kH);
  // ---- phase F: upper GRU, 512 sequential steps ----
  gru2_persistent<<<dim3(kNWG2), dim3(512), 0, stream>>>(
      Wh2b, gi2b, bi2, bh2, hx, outs2);
  // ---- phase G: e2 = tanh(outs2 @ Wl2^T + bl2), w2, final max ----
  gemm_bt<2><<<dim3(kH / 128, kS / 128), dim3(256), 0, stream>>>(
      outs2, kH, Wl2b, kH, e2b, bl2, kS, kH, kH);
  calc_w2<<<dim3(kS), dim3(64), 0, stream>>>(e2b, wa2, w2);
  final_max<<<dim3(kH / 256), dim3(256), 0, stream>>>(e2b, w2, out);
}

// Round 13
// 2483.793 us; speedup vs baseline: 1.0381x; 1.0381x over previous
//
#include <hip/hip_runtime.h>
#include <stdint.h>

typedef unsigned short u16;
typedef unsigned int u32;
typedef unsigned long long u64;
typedef __attribute__((ext_vector_type(4))) float f32x4;
typedef __attribute__((ext_vector_type(8))) short bf16x8;
typedef __attribute__((ext_vector_type(4))) u32 u32x4;

constexpr int kT = 8192;   // sequence length
constexpr int kD = 512;    // word emb dim
constexpr int kH = 2048;   // hidden
constexpr int kH3 = 6144;  // 3*H
constexpr int kS = 512;    // segments
constexpr int kSeg = 16;   // tokens per segment
constexpr int kNWG2 = 256; // persistent WGs for upper GRU
constexpr int kREP = 4;    // h-exchange replicas

__device__ __forceinline__ float bf2f(u16 u) {
  union { float f; u32 u; } v; v.u = ((u32)u) << 16; return v.f;
}
__device__ __forceinline__ u16 f2bf(float f) {
  union { float f; u32 u; } v; v.f = f;
  u32 lsb = (v.u >> 16) & 1u;
  v.u += 0x7fffu + lsb;          // round-to-nearest-even
  return (u16)(v.u >> 16);
}
// cheap packed-bf16 unpack: lo/hi half of a u32 as f32 (2 ops each)
__device__ __forceinline__ float bflo(u32 x) {
  union { float f; u32 u; } v; v.u = x << 16; return v.f;
}
__device__ __forceinline__ float bfhi(u32 x) {
  union { float f; u32 u; } v; v.u = x & 0xffff0000u; return v.f;
}
__device__ __forceinline__ float sigm(float x) { return 1.f / (1.f + expf(-x)); }

// async global->LDS, 16B per lane; LDS dest = wave-uniform base + lane*16
__device__ __forceinline__ void g2l16(const u16* g, u16* l) {
  __builtin_amdgcn_global_load_lds(
      (const __attribute__((address_space(1))) u32*)g,
      (__attribute__((address_space(3))) u32*)l, 16, 0, 0);
}

// device-coherent (sc0 sc1) bypass load/store — STOP-AND-WAIT form only.
// (r12 lesson: multi-outstanding polled loads are unsafe at HIP source level;
// the register allocator may copy pending-load dest regs before the waitcnt.)
__device__ __forceinline__ u32x4 bypass_load16(const u32* p) {
  u32x4 v;
  asm volatile("global_load_dwordx4 %0, %1, off sc0 sc1\n\ts_waitcnt vmcnt(0)"
               : "=&v"(v) : "v"(p) : "memory");
  return v;
}
__device__ __forceinline__ void bypass_store4(u32* p, u32 v) {
  asm volatile("global_store_dword %0, %1, off sc0 sc1" :: "v"(p), "v"(v) : "memory");
}

// ---------------- fused f32 -> bf16 convert (all 7 regions, one launch) ----
struct Cvt7 {
  const float* s[7];
  u16* d[7];
  u32 pref[8];   // prefix sums in float4 units
};
__global__ __launch_bounds__(256) void cvt_all(Cvt7 j, int n4tot) {
  int i = blockIdx.x * 256 + threadIdx.x;
  if (i >= n4tot) return;
  int r = 0;
  while (i >= (int)j.pref[r + 1]) ++r;   // <= 7 iterations
  const int local = i - (int)j.pref[r];
  const float4 v = ((const float4*)j.s[r])[local];
  uint2 o;
  o.x = (u32)f2bf(v.x) | ((u32)f2bf(v.y) << 16);
  o.y = (u32)f2bf(v.z) | ((u32)f2bf(v.w) << 16);
  ((uint2*)j.d[r])[local] = o;
}

// ---------------- bf16 GEMM 128x128  C = A(MxK,lda) * B(NxK,ldb)^T ---------
// 4-deep software-pipelined staging (counted vmcnt + raw s_barrier; never
// drain-0 mid-loop). EPI 1: Obf = bf16(acc)   EPI 2: Obf = bf16(tanh(acc+bias))
template<int EPI>
__global__ __launch_bounds__(256)
void gemm_bt(const u16* __restrict__ A, int lda,
             const u16* __restrict__ B, int ldb,
             u16* __restrict__ Obf, const float* __restrict__ bias,
             int M, int N, int K)
{
  __shared__ u16 ls[4 * 16384];   // 4 bufs x (A 128x64 + B 128x64) = 128 KiB
  const int tid = threadIdx.x;
  const int w = tid >> 6, lane = tid & 63;
  const int wr = w >> 1, wc = w & 1;
  const int arow0 = blockIdx.y * 128;
  const int brow0 = blockIdx.x * 128;
  const int srow = w * 32 + (lane >> 3);
  const int scol = (lane & 7) * 8;
  const u16* gA = A + (size_t)(arow0 + srow) * lda + scol;
  const u16* gB = B + (size_t)(brow0 + srow) * ldb + scol;
  const int sb = w * 32 * 64;     // wave's staging base (rows w*32..)

  f32x4 acc[4][4];
#pragma unroll
  for (int m = 0; m < 4; ++m)
#pragma unroll
    for (int n = 0; n < 4; ++n) acc[m][n] = (f32x4)0.f;

  const int fr = lane & 15;
  const int kq = lane >> 4;
  const int nk = K >> 6;

  auto stage = [&](int buf, int kt) {
    u16* la = &ls[buf * 16384 + sb];
    u16* lb = &ls[buf * 16384 + 8192 + sb];
#pragma unroll
    for (int i = 0; i < 4; ++i) g2l16(gA + (size_t)i * 8 * lda + kt, la + i * 8 * 64);
#pragma unroll
    for (int i = 0; i < 4; ++i) g2l16(gB + (size_t)i * 8 * ldb + kt, lb + i * 8 * 64);
  };

  stage(0, 0);
  if (nk > 1) stage(1, 64);
  if (nk > 2) stage(2, 128);

  for (int i = 0; i < nk; ++i) {
    if (i + 2 < nk) asm volatile("s_waitcnt vmcnt(16)" ::: "memory");
    else            asm volatile("s_waitcnt vmcnt(0)" ::: "memory");
    __builtin_amdgcn_s_barrier();
    __builtin_amdgcn_sched_barrier(0);
    if (i + 3 < nk) stage((i + 3) & 3, (i + 3) * 64);
    const u16* lsA = &ls[(i & 3) * 16384];
    const u16* lsB = lsA + 8192;
#pragma unroll
    for (int kk = 0; kk < 2; ++kk) {
      bf16x8 af[4], bq[4];
#pragma unroll
      for (int m = 0; m < 4; ++m)
        af[m] = *(const bf16x8*)&lsA[(wr * 64 + m * 16 + fr) * 64 + kk * 32 + kq * 8];
#pragma unroll
      for (int n = 0; n < 4; ++n)
        bq[n] = *(const bf16x8*)&lsB[(wc * 64 + n * 16 + fr) * 64 + kk * 32 + kq * 8];
#pragma unroll
      for (int m = 0; m < 4; ++m)
#pragma unroll
        for (int n = 0; n < 4; ++n)
          acc[m][n] = __builtin_amdgcn_mfma_f32_16x16x32_bf16(af[m], bq[n], acc[m][n], 0, 0, 0);
    }
  }

#pragma unroll
  for (int m = 0; m < 4; ++m) {
#pragma unroll
    for (int n = 0; n < 4; ++n) {
      const int row0 = arow0 + wr * 64 + m * 16 + kq * 4;
      const int col = brow0 + wc * 64 + n * 16 + fr;
      if (EPI == 1) {
#pragma unroll
        for (int i = 0; i < 4; ++i)
          Obf[(size_t)(row0 + i) * N + col] = f2bf(acc[m][n][i]);
      } else {
        const float bv = bias[col];
#pragma unroll
        for (int i = 0; i < 4; ++i)
          Obf[(size_t)(row0 + i) * N + col] = f2bf(tanhf(acc[m][n][i] + bv));
      }
    }
  }
}

// ---------------- lower-GRU gates, paired-u32 bf16 I/O ----------------
// gi32: base pointer (already offset for this step), segStride in u32 words.
// ghvalid==0: h_prev==0 -> Wh*h terms and hprev are zero (t==0 fast path).
__global__ __launch_bounds__(256) void gru1_gates(
    const u32* __restrict__ gi32, int segStride, const u16* __restrict__ gh,
    const float* __restrict__ bi, const float* __restrict__ bh,
    u16* __restrict__ h_bf, u16* __restrict__ outs_bf, int t, int ghvalid)
{
  const int idx = blockIdx.x * 256 + threadIdx.x;  // 512*1024 pairs
  const int seg = idx >> 10, jp = idx & 1023;      // j = 2*jp
  const u32* gh32 = (const u32*)gh;
  const int gbase = seg * segStride;
  const int base = seg * 3072;
  const u32 gir = gi32[gbase + jp];
  const u32 giz = gi32[gbase + 1024 + jp];
  const u32 gin = gi32[gbase + 2048 + jp];
  u32 ghr = 0, ghz = 0, ghn = 0, hp = 0;
  if (ghvalid) {
    ghr = gh32[base + jp];
    ghz = gh32[base + 1024 + jp];
    ghn = gh32[base + 2048 + jp];
    hp = ((const u32*)h_bf)[seg * 1024 + jp];
  }
  const float2 bir = *(const float2*)&bi[2 * jp];
  const float2 biz = *(const float2*)&bi[kH + 2 * jp];
  const float2 bin = *(const float2*)&bi[2 * kH + 2 * jp];
  const float2 bhr = *(const float2*)&bh[2 * jp];
  const float2 bhz = *(const float2*)&bh[kH + 2 * jp];
  const float2 bhn = *(const float2*)&bh[2 * kH + 2 * jp];
  float hn[2];
#pragma unroll
  for (int e = 0; e < 2; ++e) {
    const float gr = e ? bfhi(gir) : bflo(gir), hr = e ? bfhi(ghr) : bflo(ghr);
    const float gz = e ? bfhi(giz) : bflo(giz), hz = e ? bfhi(ghz) : bflo(ghz);
    const float gn = e ? bfhi(gin) : bflo(gin), hh = e ? bfhi(ghn) : bflo(ghn);
    const float r = sigm(gr + (e ? bir.y : bir.x) + hr + (e ? bhr.y : bhr.x));
    const float z = sigm(gz + (e ? biz.y : biz.x) + hz + (e ? bhz.y : bhz.x));
    const float n = tanhf(gn + (e ? bin.y : bin.x) + r * (hh + (e ? bhn.y : bhn.x)));
    const float hprev = e ? bfhi(hp) : bflo(hp);
    hn[e] = (1.f - z) * n + z * hprev;
  }
  const u32 packed = (u32)f2bf(hn[0]) | ((u32)f2bf(hn[1]) << 16);
  ((u32*)h_bf)[seg * 1024 + jp] = packed;
  ((u32*)outs_bf)[(size_t)(seg * kSeg + t) * 1024 + jp] = packed;
}

// ---------------- degenerate softmax weight + per-segment column max ----------------
__global__ __launch_bounds__(256) void seg_weight_max(
    const u16* __restrict__ embh, const float* __restrict__ wa,
    u16* __restrict__ seg_bf)
{
  __shared__ float wrow[16];
  const int s = blockIdx.x, tid = threadIdx.x;
  const int w = tid >> 6, lane = tid & 63;
#pragma unroll
  for (int rr = 0; rr < 4; ++rr) {
    const int r = w * 4 + rr;
    const u16* row = embh + ((size_t)s * kSeg + r) * kH;
    float p = 0.f;
#pragma unroll
    for (int k = 0; k < 32; ++k) {
      const int c = lane + 64 * k;
      p += bf2f(row[c]) * wa[c];
    }
#pragma unroll
    for (int off = 32; off; off >>= 1) p += __shfl_down(p, off, 64);
    if (lane == 0) { const float e = expf(p); wrow[r] = e / (e + 1e-4f); }
  }
  __syncthreads();
#pragma unroll
  for (int i = 0; i < 8; ++i) {
    const int c = tid + 256 * i;
    float m = -1e30f;
#pragma unroll
    for (int r = 0; r < 16; ++r)
      m = fmaxf(m, wrow[r] * bf2f(embh[((size_t)s * kSeg + r) * kH + c]));
    seg_bf[(size_t)s * kH + c] = f2bf(m);
  }
}

// ---------------- upper GRU: persistent, 512 steps (r9 v5, verified) -------
// Gate-aligned waves (wave w owns element jj=wg*8+w; its 3 register-resident
// rows are that element's r/z/n rows), conflict-free h reads, gates at
// lane 0, tagged LDS handoff, wave-0 coalesced publish. Stop-and-wait
// self-validating poll (word = (bf16<<16)|step_tag).
__global__ __launch_bounds__(512)
void gru2_persistent(const u16* __restrict__ Wh2bf, const u16* __restrict__ gi2b,
                     const float* __restrict__ bi2, const float* __restrict__ bh2,
                     u32* __restrict__ hx,        // [2][kREP][2048] tagged u32
                     u16* __restrict__ outs2)     // 512*2048 bf16
{
  __shared__ u32 hlb[2][1024];                // 8 KiB: h packed pairs, dbuf
  __shared__ float gil_all[512 * 24];         // 48 KiB gi2 slice
  __shared__ u32 hnlt[8];                     // tagged per-wave results
  const int wg = blockIdx.x, tid = threadIdx.x;
  const int g0 = wg * 8;
  const int rep = wg & (kREP - 1);
  const int w = tid >> 6, lane = tid & 63;
  const int jj = g0 + w;                      // this wave's output element

  // ---- weights: r/z/n rows of element jj; cols q*512 + lane*8 .. +8 ----
  u32 wr_[16], wz_[16], wn_[16];
  {
    const u32* rr = (const u32*)(Wh2bf + (size_t)jj * kH);
    const u32* rz = (const u32*)(Wh2bf + (size_t)(kH + jj) * kH);
    const u32* rn = (const u32*)(Wh2bf + (size_t)(2 * kH + jj) * kH);
#pragma unroll
    for (int q = 0; q < 4; ++q)
#pragma unroll
      for (int i = 0; i < 4; ++i) {
        const int idx = q * 256 + lane * 4 + i;
        wr_[q * 4 + i] = rr[idx];
        wz_[q * 4 + i] = rz[idx];
        wn_[q * 4 + i] = rn[idx];
      }
  }
  for (int i = tid; i < 512 * 24; i += 512) {
    const int t = i / 24, idx = i - t * 24;
    gil_all[i] = bf2f(gi2b[(size_t)t * kH3 + (idx >> 3) * kH + g0 + (idx & 7)]);
  }
  const float bir = bi2[jj], biz = bi2[kH + jj], bin = bi2[2 * kH + jj];
  const float bhr = bh2[jj], bhz = bh2[kH + jj], bhn = bh2[2 * kH + jj];
  if (tid < 8) hnlt[tid] = 0;
  __syncthreads();

  for (int t = 0; t < 512; ++t) {
    const int par = t & 1;
    const u32 want = (u32)t & 0xffffu;
    const u32* p = hx + ((size_t)par * kREP + rep) * 2048 + 4 * tid;
    u32x4 v = bypass_load16(p);
    for (;;) {
      const u32 bad = ((v.x ^ want) | (v.y ^ want) | (v.z ^ want) | (v.w ^ want)) & 0xffffu;
      if (!__any((int)bad)) break;
      if (bad) v = bypass_load16(p);
    }
    hlb[par][2 * tid]     = (v.x >> 16) | (v.y & 0xffff0000u);
    hlb[par][2 * tid + 1] = (v.z >> 16) | (v.w & 0xffff0000u);
    __syncthreads();
    // ---- register matvec: conflict-free h reads, 3 gate rows per lane ----
    const uint4* hp4 = (const uint4*)&hlb[par][0];
    float ar = 0.f, az = 0.f, an = 0.f;
#pragma unroll
    for (int q = 0; q < 4; ++q) {
      const uint4 hv = hp4[q * 64 + lane];
      const float hf[8] = { bflo(hv.x), bfhi(hv.x), bflo(hv.y), bfhi(hv.y),
                            bflo(hv.z), bfhi(hv.z), bflo(hv.w), bfhi(hv.w) };
#pragma unroll
      for (int i = 0; i < 4; ++i) {
        const u32 wrv = wr_[q * 4 + i], wzv = wz_[q * 4 + i], wnv = wn_[q * 4 + i];
        ar += bflo(wrv) * hf[2 * i] + bfhi(wrv) * hf[2 * i + 1];
        az += bflo(wzv) * hf[2 * i] + bfhi(wzv) * hf[2 * i + 1];
        an += bflo(wnv) * hf[2 * i] + bfhi(wnv) * hf[2 * i + 1];
      }
    }
#pragma unroll
    for (int off = 32; off; off >>= 1) {
      ar += __shfl_down(ar, off, 64);
      az += __shfl_down(az, off, 64);
      an += __shfl_down(an, off, 64);
    }
    // ---- gates at lane 0 -> tagged LDS handoff (no barrier) ----
    if (lane == 0) {
      const float r = sigm(gil_all[t * 24 + w] + bir + ar + bhr);
      const float z = sigm(gil_all[t * 24 + 8 + w] + biz + az + bhz);
      const float n = tanhf(gil_all[t * 24 + 16 + w] + bin + r * (an + bhn));
      const u32 hw = hlb[par][jj >> 1];
      const float hprev = (jj & 1) ? bfhi(hw) : bflo(hw);
      const u16 hb = f2bf((1.f - z) * n + z * hprev);
      const u32 word = ((u32)hb << 16) | ((u32)(t + 1) & 0xffffu);
      __hip_atomic_store(&hnlt[w], word, __ATOMIC_RELAXED, __HIP_MEMORY_SCOPE_WORKGROUP);
    }
    // ---- wave 0: collect via LDS spin, coalesced publish ----
    if (w == 0) {
      const u32 want1 = (u32)(t + 1) & 0xffffu;
      u32 x = 0;
      if (lane < 8) {
        for (;;) {
          x = __hip_atomic_load(&hnlt[lane], __ATOMIC_RELAXED, __HIP_MEMORY_SCOPE_WORKGROUP);
          if ((x & 0xffffu) == want1) break;
        }
      }
      const u32 word = __shfl(x, lane & 7, 64);
      if (lane < 4 * 8) {
        const int orep = lane >> 3;
        bypass_store4(hx + ((size_t)(1 - par) * kREP + orep) * 2048 + g0 + (lane & 7), word);
      }
      if (lane < 8) outs2[(size_t)t * kH + g0 + lane] = (u16)(x >> 16);
    }
  }
}

// ---------------- w2 then final column max ----------------
__global__ void calc_w2(const u16* __restrict__ e2, const float* __restrict__ wa2,
                        float* __restrict__ w2) {
  const int s = blockIdx.x, lane = threadIdx.x;  // 64 threads
  float p = 0.f;
#pragma unroll
  for (int k = 0; k < 32; ++k) {
    const int c = lane + 64 * k;
    p += bf2f(e2[(size_t)s * kH + c]) * wa2[c];
  }
#pragma unroll
  for (int off = 32; off; off >>= 1) p += __shfl_down(p, off, 64);
  if (lane == 0) { const float e = expf(p); w2[s] = e / (e + 1e-4f); }
}

__global__ void final_max(const u16* __restrict__ e2, const float* __restrict__ w2,
                          float* __restrict__ out) {
  const int j = blockIdx.x * blockDim.x + threadIdx.x;  // 2048
  float m = -1e30f;
  for (int s = 0; s < 512; ++s)
    m = fmaxf(m, w2[s] * bf2f(e2[(size_t)s * kH + j]));
  out[j] = m;
}

// ---------------- host ----------------
extern "C" void kernel_launch(void* const* d_in, const int* in_sizes, int n_in,
                              void* d_out, int out_size, void* d_ws, size_t ws_size,
                              hipStream_t stream)
{
  (void)in_sizes; (void)n_in; (void)out_size;
  const float* sent = (const float*)d_in[0];
  const float* Wi1f = (const float*)d_in[1];
  const float* Wh1f = (const float*)d_in[2];
  const float* bi1  = (const float*)d_in[3];
  const float* bh1  = (const float*)d_in[4];
  const float* Wi2f = (const float*)d_in[5];
  const float* Wh2f = (const float*)d_in[6];
  const float* bi2  = (const float*)d_in[7];
  const float* bh2  = (const float*)d_in[8];
  const float* Wlf  = (const float*)d_in[9];
  const float* bl   = (const float*)d_in[10];
  const float* wa   = (const float*)d_in[11];
  const float* Wl2f = (const float*)d_in[12];
  const float* bl2  = (const float*)d_in[13];
  const float* wa2  = (const float*)d_in[14];
  float* out = (float*)d_out;

  char* base = (char*)d_ws;
  size_t off = 0;
  auto alloc = [&](size_t b) { char* p = base + off; off += (b + 255) & ~(size_t)255; return p; };
  u16* sent_bf = (u16*)alloc((size_t)kT * kD * 2);   // dead after GI/phase B -> embh alias
  u16* Wi1b    = (u16*)alloc((size_t)kH3 * kD * 2);
  u16* Wh1b    = (u16*)alloc((size_t)kH3 * kH * 2);
  u16* Wi2b    = (u16*)alloc((size_t)kH3 * kH * 2);
  u16* Wh2b    = (u16*)alloc((size_t)kH3 * kH * 2);
  u16* Wlb     = (u16*)alloc((size_t)kH * kH * 2);
  u16* Wl2b    = (u16*)alloc((size_t)kH * kH * 2);
  u16* gi_buf  = (u16*)alloc((size_t)kS * kH3 * 2);  // per-step fallback
  u16* gh_buf  = (u16*)alloc((size_t)kS * kH3 * 2);
  u16* h1b     = (u16*)alloc((size_t)kS * kH * 2);
  u16* outs_bf = (u16*)alloc((size_t)kT * kH * 2);
  u16* seg_bf  = (u16*)alloc((size_t)kS * kH * 2);
  u32* hx      = (u32*)alloc((size_t)2 * kREP * 2048 * 4);
  u16* outs2   = (u16*)alloc((size_t)kS * kH * 2);
  u16* e2b     = (u16*)alloc((size_t)kS * kH * 2);
  float* w2    = (float*)alloc(kS * 4);
  // optional fused-gi buffer (100.7 MB): engage only if ws is big enough
  const size_t off_before_gi = off;
  u16* gi_all  = (u16*)alloc((size_t)kT * kH3 * 2);
  const bool fused_gi = (off <= ws_size);
  if (!fused_gi) off = off_before_gi;
  // aliases over dead regions
  u16* embh = sent_bf;   // 33.5 MB fits in sent_bf+Wi1b+Wh1b (39.8 MB)
  u16* gi2b = gi_buf;

  (void)hipMemsetAsync(hx, 0, (size_t)2 * kREP * 2048 * 4, stream);

  // ---- fused conversion: all 7 regions, one launch ----
  {
    Cvt7 j;
    const float* srcs[7] = { sent, Wi1f, Wh1f, Wi2f, Wh2f, Wlf, Wl2f };
    u16* dsts[7] = { sent_bf, Wi1b, Wh1b, Wi2b, Wh2b, Wlb, Wl2b };
    const u32 n4s[7] = { kT * kD / 4, kH3 * kD / 4, kH3 * kH / 4, kH3 * kH / 4,
                         kH3 * kH / 4, kH * kH / 4, kH * kH / 4 };
    u32 acc = 0;
    for (int r = 0; r < 7; ++r) { j.s[r] = srcs[r]; j.d[r] = dsts[r]; j.pref[r] = acc; acc += n4s[r]; }
    j.pref[7] = acc;
    cvt_all<<<dim3((acc + 255) / 256), dim3(256), 0, stream>>>(j, (int)acc);
  }

  // ---- phase B: lower GRU, 16 batched steps over 512 independent chains ----
  if (fused_gi) {
    gemm_bt<1><<<dim3(kH3 / 128, kT / 128), dim3(256), 0, stream>>>(
        sent_bf, kD, Wi1b, kD, gi_all, nullptr, kT, kH3, kD);
  }
  for (int t = 0; t < kSeg; ++t) {
    if (t > 0) {
      gemm_bt<1><<<dim3(kH3 / 128, kS / 128), dim3(256), 0, stream>>>(
          h1b, kH, Wh1b, kH, gh_buf, nullptr, kS, kH3, kH);
    }
    const u32* gi32;
    int segStride;
    if (fused_gi) {
      gi32 = (const u32*)gi_all + (size_t)t * 3072;   // token = seg*16 + t
      segStride = kSeg * 3072;
    } else {
      gemm_bt<1><<<dim3(kH3 / 128, kS / 128), dim3(256), 0, stream>>>(
          sent_bf + t * kD, kSeg * kD, Wi1b, kD, gi_buf, nullptr, kS, kH3, kD);
      gi32 = (const u32*)gi_buf;
      segStride = 3072;
    }
    gru1_gates<<<dim3(kS * kH / 512), dim3(256), 0, stream>>>(
        gi32, segStride, gh_buf, bi1, bh1, h1b, outs_bf, t, t > 0 ? 1 : 0);
  }
  // ---- phase C: emb_h = tanh(outs @ Wl^T + bl) ----
  gemm_bt<2><<<dim3(kH / 128, kT / 128), dim3(256), 0, stream>>>(
      outs_bf, kH, Wlb, kH, embh, bl, kT, kH, kH);
  // ---- phase D: w, weighted, segment max ----
  seg_weight_max<<<dim3(kS), dim3(256), 0, stream>>>(embh, wa, seg_bf);
  // ---- phase E: gi2 = seg @ Wi2^T (bf16) ----
  gemm_bt<1><<<dim3(kH3 / 128, kS / 128), dim3(256), 0, stream>>>(
      seg_bf, kH, Wi2b, kH, gi2b, nullptr, kS, kH3, kH);
  // ---- phase F: upper GRU, 512 sequential steps ----
  gru2_persistent<<<dim3(kNWG2), dim3(512), 0, stream>>>(
      Wh2b, gi2b, bi2, bh2, hx, outs2);
  // ---- phase G: e2 = tanh(outs2 @ Wl2^T + bl2), w2, final max ----
  gemm_bt<2><<<dim3(kH / 128, kS / 128), dim3(256), 0, stream>>>(
      outs2, kH, Wl2b, kH, e2b, bl2, kS, kH, kH);
  calc_w2<<<dim3(kS), dim3(64), 0, stream>>>(e2b, wa2, w2);
  final_max<<<dim3(kH / 256), dim3(256), 0, stream>>>(e2b, w2, out);
}